// Round 2
// baseline (799.747 us; speedup 1.0000x reference)
//
#include <hip/hip_runtime.h>
#include <cstddef>

#define NC 16
#define HID 128
#define IMH 256
#define IMW 256
#define NB 32
#define TILE 16
#define HR 18    // halo region = TILE+2 (pixels needing the MLP)
#define XS 20    // staged X region = TILE+4 (sobel halo of HR)
#define NTHREADS 384
#define WROW 36  // packed weight row: [b1 | w1eff[18] | w2T[16] | pad] (144B, 16B-aligned)

// Collapse w1's 48 columns into 18 effective feature columns (torch grouped layout).
__global__ void prep_weights(const float* __restrict__ w1,
                             const float* __restrict__ b1,
                             const float* __restrict__ w2,
                             float* __restrict__ wpack) {
    int j = threadIdx.x;
    if (j >= HID) return;
    const int starts[18] = {0,3,6,9,12,15,16,18,21,24,27,30,32,33,36,39,42,45};
    const int lens[18]   = {3,3,3,3,3,1,2,3,3,3,3,2,1,3,3,3,3,3};
    float* row = wpack + j * WROW;
    row[0] = b1[j];
    #pragma unroll
    for (int f = 0; f < 18; ++f) {
        float s = 0.f;
        for (int k = 0; k < lens[f]; ++k) s += w1[j*48 + starts[f] + k];
        row[1+f] = s;
    }
    #pragma unroll
    for (int c = 0; c < NC; ++c) row[19+c] = w2[c*HID + j];
    row[35] = 0.f;
}

__global__ __launch_bounds__(NTHREADS, 2)
void nca_fused(const float* __restrict__ X,
               const float* __restrict__ rand_u,
               const float* __restrict__ wpack,
               float* __restrict__ out) {
    __shared__ float sX[NC][XS][XS];      // staged X tile, zero-padded OOB (25.6 KB)
    __shared__ float sW[HID * WROW];      // packed weights (18 KB)
    __shared__ float sA[HR][HR];          // Xn alpha (post-update), 0 for OOB (1.3 KB)

    const int t  = threadIdx.x;
    const int x0 = blockIdx.x * TILE;
    const int y0 = blockIdx.y * TILE;
    const int b  = blockIdx.z;

    const float* Xb = X + (size_t)b * NC * IMH * IMW;

    // ---- stage weights: 4608 floats, coalesced ----
    for (int e = t; e < HID * WROW; e += NTHREADS) sW[e] = wpack[e];

    // ---- stage X: 16 channels x 20x20, origin at tile-(-2,-2) ----
    for (int e = t; e < NC*XS*XS; e += NTHREADS) {
        int ch  = e / (XS*XS);
        int rem = e - ch*(XS*XS);
        int yy  = rem / XS;
        int xx  = rem - yy*XS;
        int gy = y0 + yy - 2, gx = x0 + xx - 2;
        float v = 0.f;
        if (gy >= 0 && gy < IMH && gx >= 0 && gx < IMW)
            v = Xb[(size_t)ch*IMH*IMW + (size_t)gy*IMW + gx];
        (&sX[0][0][0])[e] = v;
    }
    __syncthreads();

    // ---- per-pixel MLP at all 18x18 halo pixels (threads 0..323) ----
    float Xn[NC];
    #pragma unroll
    for (int c = 0; c < NC; ++c) Xn[c] = 0.f;
    bool interior = false;
    int hy = 0, hx = 0, gy = 0, gx = 0;

    if (t < HR*HR) {
        hy = t / HR; hx = t - hy*HR;
        gy = y0 + hy - 1; gx = x0 + hx - 1;
        const int sy = hy + 1, sxx = hx + 1;  // staged coords of this pixel

        float f[18];
        #pragma unroll
        for (int c = 0; c < 6; ++c) f[c] = sX[c][sy][sxx];
        #pragma unroll
        for (int i = 0; i < 6; ++i) {   // sobel_x on ch 5..10 -> f[6..11]
            const int ch = 5 + i;
            f[6+i] = ( -     sX[ch][sy-1][sxx-1] +     sX[ch][sy-1][sxx+1]
                       - 2.f*sX[ch][sy  ][sxx-1] + 2.f*sX[ch][sy  ][sxx+1]
                       -     sX[ch][sy+1][sxx-1] +     sX[ch][sy+1][sxx+1] ) * 0.125f;
        }
        #pragma unroll
        for (int i = 0; i < 6; ++i) {   // sobel_y on ch 10..15 -> f[12..17]
            const int ch = 10 + i;
            f[12+i] = ( -sX[ch][sy-1][sxx-1] - 2.f*sX[ch][sy-1][sxx] - sX[ch][sy-1][sxx+1]
                        +sX[ch][sy+1][sxx-1] + 2.f*sX[ch][sy+1][sxx] + sX[ch][sy+1][sxx+1] ) * 0.125f;
        }

        // fetch mask early so it overlaps the MLP
        const bool inb = (gy >= 0 && gy < IMH && gx >= 0 && gx < IMW);
        float m = 0.f;
        if (inb) m = (rand_u[(size_t)b*IMH*IMW + (size_t)gy*IMW + gx] < 0.5f) ? 1.f : 0.f;

        float acc[NC];
        #pragma unroll
        for (int c = 0; c < NC; ++c) acc[c] = 0.f;

        // 128 hidden units; weight row = 9x float4 from LDS (uniform addr -> broadcast)
        #pragma unroll 2
        for (int j = 0; j < HID; ++j) {
            const float4* row = (const float4*)(sW + j * WROW);
            const float4 q0 = row[0], q1 = row[1], q2 = row[2], q3 = row[3], q4 = row[4];
            const float4 q5 = row[5], q6 = row[6], q7 = row[7], q8 = row[8];
            float hj = q0.x;                       // b1
            hj = fmaf(q0.y, f[0], hj);  hj = fmaf(q0.z, f[1], hj);  hj = fmaf(q0.w, f[2], hj);
            hj = fmaf(q1.x, f[3], hj);  hj = fmaf(q1.y, f[4], hj);  hj = fmaf(q1.z, f[5], hj);
            hj = fmaf(q1.w, f[6], hj);  hj = fmaf(q2.x, f[7], hj);  hj = fmaf(q2.y, f[8], hj);
            hj = fmaf(q2.z, f[9], hj);  hj = fmaf(q2.w, f[10], hj); hj = fmaf(q3.x, f[11], hj);
            hj = fmaf(q3.y, f[12], hj); hj = fmaf(q3.z, f[13], hj); hj = fmaf(q3.w, f[14], hj);
            hj = fmaf(q4.x, f[15], hj); hj = fmaf(q4.y, f[16], hj); hj = fmaf(q4.z, f[17], hj);
            hj = fmaxf(hj, 0.f);
            acc[0]  = fmaf(q4.w, hj, acc[0]);
            acc[1]  = fmaf(q5.x, hj, acc[1]);  acc[2]  = fmaf(q5.y, hj, acc[2]);
            acc[3]  = fmaf(q5.z, hj, acc[3]);  acc[4]  = fmaf(q5.w, hj, acc[4]);
            acc[5]  = fmaf(q6.x, hj, acc[5]);  acc[6]  = fmaf(q6.y, hj, acc[6]);
            acc[7]  = fmaf(q6.z, hj, acc[7]);  acc[8]  = fmaf(q6.w, hj, acc[8]);
            acc[9]  = fmaf(q7.x, hj, acc[9]);  acc[10] = fmaf(q7.y, hj, acc[10]);
            acc[11] = fmaf(q7.z, hj, acc[11]); acc[12] = fmaf(q7.w, hj, acc[12]);
            acc[13] = fmaf(q8.x, hj, acc[13]); acc[14] = fmaf(q8.y, hj, acc[14]);
            acc[15] = fmaf(q8.z, hj, acc[15]);
        }

        #pragma unroll
        for (int c = 0; c < NC; ++c) Xn[c] = sX[c][sy][sxx] + acc[c]*m;
        sA[hy][hx] = inb ? Xn[3] : 0.f;   // 0 acts as -inf for the >0.1 test
        interior = (hy >= 1 && hy <= TILE && hx >= 1 && hx <= TILE);
    }
    __syncthreads();

    // ---- masks + write (interior pixels only) ----
    if (interior) {
        float mpre  = sX[3][hy][hx];      // staged rows hy..hy+2 = sy-1..sy+1
        float mpost = sA[hy-1][hx-1];
        #pragma unroll
        for (int dy = 0; dy < 3; ++dy)
            #pragma unroll
            for (int dxx = 0; dxx < 3; ++dxx) {
                mpre  = fmaxf(mpre,  sX[3][hy+dy][hx+dxx]);
                mpost = fmaxf(mpost, sA[hy-1+dy][hx-1+dxx]);
            }
        const float live = (mpre > 0.1f && mpost > 0.1f) ? 1.f : 0.f;
        float* ob = out + (size_t)b*NC*IMH*IMW + (size_t)gy*IMW + gx;
        #pragma unroll
        for (int c = 0; c < NC; ++c) ob[(size_t)c*IMH*IMW] = Xn[c]*live;
    }
}

extern "C" void kernel_launch(void* const* d_in, const int* in_sizes, int n_in,
                              void* d_out, int out_size, void* d_ws, size_t ws_size,
                              hipStream_t stream) {
    const float* X  = (const float*)d_in[0];
    const float* w1 = (const float*)d_in[1];
    const float* b1 = (const float*)d_in[2];
    const float* w2 = (const float*)d_in[3];
    const float* ru = (const float*)d_in[4];
    float* out   = (float*)d_out;
    float* wpack = (float*)d_ws;   // 128*36*4 = 18432 bytes

    prep_weights<<<1, 128, 0, stream>>>(w1, b1, w2, wpack);

    dim3 grid(IMW/TILE, IMH/TILE, NB);
    nca_fused<<<grid, NTHREADS, 0, stream>>>(X, ru, wpack, out);
}

// Round 3
// 459.586 us; speedup vs baseline: 1.7401x; 1.7401x over previous
//
#include <hip/hip_runtime.h>
#include <cstddef>

#define NC 16
#define HID 128
#define IMH 256
#define IMW 256
#define NB 32
#define TILE 16
#define HR 18     // halo region = TILE+2 (pixels needing the MLP)
#define XS 20     // staged X region = TILE+4 (sobel halo of HR)
#define NTHREADS 384
#define WROW 36   // packed weight row: [b1 | w1eff[18] | w2T[16] | pad] (144B)
#define SDXS 17   // sDX row stride (pad to kill 16-stride bank conflicts)

// Collapse w1's 48 columns into 18 effective feature columns (torch grouped layout).
__global__ void prep_weights(const float* __restrict__ w1,
                             const float* __restrict__ b1,
                             const float* __restrict__ w2,
                             float* __restrict__ wpack) {
    int j = threadIdx.x;
    if (j >= HID) return;
    const int starts[18] = {0,3,6,9,12,15,16,18,21,24,27,30,32,33,36,39,42,45};
    const int lens[18]   = {3,3,3,3,3,1,2,3,3,3,3,2,1,3,3,3,3,3};
    float* row = wpack + j * WROW;
    row[0] = b1[j];
    #pragma unroll
    for (int f = 0; f < 18; ++f) {
        float s = 0.f;
        for (int k = 0; k < lens[f]; ++k) s += w1[j*48 + starts[f] + k];
        row[1+f] = s;
    }
    #pragma unroll
    for (int c = 0; c < NC; ++c) row[19+c] = w2[c*HID + j];
    row[35] = 0.f;
}

__global__ __launch_bounds__(NTHREADS, 2)
void nca_fused(const float* __restrict__ X,
               const float* __restrict__ rand_u,
               const float* __restrict__ wpack,
               float* __restrict__ out) {
    __shared__ float sX[NC][XS][XS];        // staged X tile, zero-padded OOB (25.6 KB)
    __shared__ float sDX[HR*HR][SDXS];      // dx*mask per halo pixel (22 KB)
    __shared__ float sA[HR][HR];            // Xn alpha (post-update)
    __shared__ int   sList[HR*HR];          // compacted active-pixel ids
    __shared__ int   sCount;

    const int t  = threadIdx.x;
    const int x0 = blockIdx.x * TILE;
    const int y0 = blockIdx.y * TILE;
    const int b  = blockIdx.z;

    const float* Xb = X + (size_t)b * NC * IMH * IMW;

    // ---- phase 1: init + stage X ----
    if (t == 0) sCount = 0;
    for (int e = t; e < HR*HR*SDXS; e += NTHREADS) (&sDX[0][0])[e] = 0.f;
    for (int e = t; e < NC*XS*XS; e += NTHREADS) {
        int ch  = e / (XS*XS);
        int rem = e - ch*(XS*XS);
        int yy  = rem / XS;
        int xx  = rem - yy*XS;
        int gy = y0 + yy - 2, gx = x0 + xx - 2;
        float v = 0.f;
        if (gy >= 0 && gy < IMH && gx >= 0 && gx < IMW)
            v = Xb[(size_t)ch*IMH*IMW + (size_t)gy*IMW + gx];
        (&sX[0][0][0])[e] = v;
    }
    __syncthreads();

    // ---- phase 2: stochastic mask -> compact active pixels ----
    int hy = 0, hx = 0, gy = 0, gx = 0;
    bool halo = (t < HR*HR);
    bool active = false;
    if (halo) {
        hy = t / HR; hx = t - hy*HR;
        gy = y0 + hy - 1; gx = x0 + hx - 1;
        if (gy >= 0 && gy < IMH && gx >= 0 && gx < IMW)
            active = rand_u[(size_t)b*IMH*IMW + (size_t)gy*IMW + gx] < 0.5f;
    }
    {
        unsigned long long wm = __ballot(active);
        if (wm) {
            const int lane = t & 63;
            int base = 0;
            if (lane == 0) base = atomicAdd(&sCount, __popcll(wm));
            base = __shfl(base, 0, 64);
            if (active)
                sList[base + __popcll(wm & ((1ull << lane) - 1ull))] = t;
        }
    }
    __syncthreads();
    const int count = sCount;

    // ---- phase 3: MLP only for active pixels (wave-uniform skip) ----
    // Branch condition is a ballot => SGPR => uniform control flow inside,
    // so the wpack loads (uniform address) scalarize to s_load on the scalar pipe.
    unsigned long long runmask = __ballot(t < count);
    if (runmask != 0ull) {
        const int idx = (t < count) ? t : 0;
        const int pid = sList[idx];
        const int py = pid / HR, px = pid - py*HR;
        const int sy = py + 1, sxc = px + 1;

        float f[18];
        #pragma unroll
        for (int c = 0; c < 6; ++c) f[c] = sX[c][sy][sxc];
        #pragma unroll
        for (int i = 0; i < 6; ++i) {   // sobel_x on ch 5..10 -> f[6..11]
            const int ch = 5 + i;
            f[6+i] = ( -     sX[ch][sy-1][sxc-1] +     sX[ch][sy-1][sxc+1]
                       - 2.f*sX[ch][sy  ][sxc-1] + 2.f*sX[ch][sy  ][sxc+1]
                       -     sX[ch][sy+1][sxc-1] +     sX[ch][sy+1][sxc+1] ) * 0.125f;
        }
        #pragma unroll
        for (int i = 0; i < 6; ++i) {   // sobel_y on ch 10..15 -> f[12..17]
            const int ch = 10 + i;
            f[12+i] = ( -sX[ch][sy-1][sxc-1] - 2.f*sX[ch][sy-1][sxc] - sX[ch][sy-1][sxc+1]
                        +sX[ch][sy+1][sxc-1] + 2.f*sX[ch][sy+1][sxc] + sX[ch][sy+1][sxc+1] ) * 0.125f;
        }

        float acc[NC];
        #pragma unroll
        for (int c = 0; c < NC; ++c) acc[c] = 0.f;

        #pragma unroll 2
        for (int j = 0; j < HID; ++j) {
            const float4* row = (const float4*)(wpack + j*WROW);
            const float4 q0 = row[0], q1 = row[1], q2 = row[2], q3 = row[3], q4 = row[4];
            const float4 q5 = row[5], q6 = row[6], q7 = row[7], q8 = row[8];
            float hj = q0.x;                       // b1
            hj = fmaf(q0.y, f[0], hj);  hj = fmaf(q0.z, f[1], hj);  hj = fmaf(q0.w, f[2], hj);
            hj = fmaf(q1.x, f[3], hj);  hj = fmaf(q1.y, f[4], hj);  hj = fmaf(q1.z, f[5], hj);
            hj = fmaf(q1.w, f[6], hj);  hj = fmaf(q2.x, f[7], hj);  hj = fmaf(q2.y, f[8], hj);
            hj = fmaf(q2.z, f[9], hj);  hj = fmaf(q2.w, f[10], hj); hj = fmaf(q3.x, f[11], hj);
            hj = fmaf(q3.y, f[12], hj); hj = fmaf(q3.z, f[13], hj); hj = fmaf(q3.w, f[14], hj);
            hj = fmaf(q4.x, f[15], hj); hj = fmaf(q4.y, f[16], hj); hj = fmaf(q4.z, f[17], hj);
            hj = fmaxf(hj, 0.f);
            acc[0]  = fmaf(q4.w, hj, acc[0]);
            acc[1]  = fmaf(q5.x, hj, acc[1]);  acc[2]  = fmaf(q5.y, hj, acc[2]);
            acc[3]  = fmaf(q5.z, hj, acc[3]);  acc[4]  = fmaf(q5.w, hj, acc[4]);
            acc[5]  = fmaf(q6.x, hj, acc[5]);  acc[6]  = fmaf(q6.y, hj, acc[6]);
            acc[7]  = fmaf(q6.z, hj, acc[7]);  acc[8]  = fmaf(q6.w, hj, acc[8]);
            acc[9]  = fmaf(q7.x, hj, acc[9]);  acc[10] = fmaf(q7.y, hj, acc[10]);
            acc[11] = fmaf(q7.z, hj, acc[11]); acc[12] = fmaf(q7.w, hj, acc[12]);
            acc[13] = fmaf(q8.x, hj, acc[13]); acc[14] = fmaf(q8.y, hj, acc[14]);
            acc[15] = fmaf(q8.z, hj, acc[15]);
        }

        if (t < count) {
            #pragma unroll
            for (int c = 0; c < NC; ++c) sDX[pid][c] = acc[c];
        }
    }
    __syncthreads();

    // ---- phase 4: Xn = X + dx (dx already mask-gated; 0 for inactive/OOB) ----
    float Xn[NC];
    #pragma unroll
    for (int c = 0; c < NC; ++c) Xn[c] = 0.f;
    if (halo) {
        const int sy = hy + 1, sxc = hx + 1;
        #pragma unroll
        for (int c = 0; c < NC; ++c) Xn[c] = sX[c][sy][sxc] + sDX[t][c];
        sA[hy][hx] = Xn[3];   // OOB halo: 0 + 0 = 0, acts as -inf for > 0.1
    }
    __syncthreads();

    // ---- phase 5: masks + write (interior pixels only) ----
    if (halo && hy >= 1 && hy <= TILE && hx >= 1 && hx <= TILE) {
        float mpre  = sX[3][hy][hx];
        float mpost = sA[hy-1][hx-1];
        #pragma unroll
        for (int dy = 0; dy < 3; ++dy)
            #pragma unroll
            for (int dxx = 0; dxx < 3; ++dxx) {
                mpre  = fmaxf(mpre,  sX[3][hy+dy][hx+dxx]);
                mpost = fmaxf(mpost, sA[hy-1+dy][hx-1+dxx]);
            }
        const float live = (mpre > 0.1f && mpost > 0.1f) ? 1.f : 0.f;
        float* ob = out + (size_t)b*NC*IMH*IMW + (size_t)gy*IMW + gx;
        #pragma unroll
        for (int c = 0; c < NC; ++c) ob[(size_t)c*IMH*IMW] = Xn[c]*live;
    }
}

extern "C" void kernel_launch(void* const* d_in, const int* in_sizes, int n_in,
                              void* d_out, int out_size, void* d_ws, size_t ws_size,
                              hipStream_t stream) {
    const float* X  = (const float*)d_in[0];
    const float* w1 = (const float*)d_in[1];
    const float* b1 = (const float*)d_in[2];
    const float* w2 = (const float*)d_in[3];
    const float* ru = (const float*)d_in[4];
    float* out   = (float*)d_out;
    float* wpack = (float*)d_ws;   // 128*36*4 = 18432 bytes

    prep_weights<<<1, 128, 0, stream>>>(w1, b1, w2, wpack);

    dim3 grid(IMW/TILE, IMH/TILE, NB);
    nca_fused<<<grid, NTHREADS, 0, stream>>>(X, ru, wpack, out);
}

// Round 4
// 304.662 us; speedup vs baseline: 2.6250x; 1.5085x over previous
//
#include <hip/hip_runtime.h>
#include <hip/hip_bf16.h>
#include <cstddef>

#define NC 16
#define HID 128
#define IMH 256
#define IMW 256
#define NB 32
#define TILE 16
#define HR 18      // halo region (pixels needing the MLP): 18x18 = 324
#define XSR 20     // staged rows
#define XSC 24     // staged cols (16B-aligned chunks)
#define NTHREADS 256
#define WROW 36
#define NPIX (HR*HR)
#define NTILES 21  // ceil(324/16)
#define FSTR 40    // feat row stride (u16); 80B = 5*16 -> b128-aligned rows
#define HSTR 136   // h row stride (u16); 272B = 17*16 -> b128-aligned rows

typedef __attribute__((ext_vector_type(8))) short bf16x8;
typedef __attribute__((ext_vector_type(4))) float f32x4;

static __device__ __forceinline__ unsigned short f2bf(float x) {
    union { __hip_bfloat16 b; unsigned short u; } v;
    v.b = __float2bfloat16(x);
    return v.u;
}
static __device__ __forceinline__ float bf2f(unsigned short u) {
    union { __hip_bfloat16 b; unsigned short u; } v;
    v.u = u;
    return __bfloat162float(v.b);
}

// ---------------- weight prep ----------------
// wpack (f32)  : [128][36] = [b1 | w1eff[18] | w2T[16] | pad]  (exact fp32, for fallback)
// w1pb (bf16)  : [(col*4+g)*8 + r] = w1eff[col][g*8+r], zero for k>=18  (B-frag friendly)
// w2pb (bf16)  : [((kc*4+g)*16 + ch)*8 + r] = w2[ch][kc*32+g*8+r]
__global__ void prep_weights(const float* __restrict__ w1,
                             const float* __restrict__ b1,
                             const float* __restrict__ w2,
                             float* __restrict__ wpack,
                             unsigned short* __restrict__ w1pb,
                             unsigned short* __restrict__ w2pb) {
    int j = threadIdx.x;
    if (j >= HID) return;
    const int starts[18] = {0,3,6,9,12,15,16,18,21,24,27,30,32,33,36,39,42,45};
    const int lens[18]   = {3,3,3,3,3,1,2,3,3,3,3,2,1,3,3,3,3,3};
    float* row = wpack + j * WROW;
    row[0] = b1[j];
    float we[18];
    #pragma unroll
    for (int f = 0; f < 18; ++f) {
        float s = 0.f;
        for (int k = 0; k < lens[f]; ++k) s += w1[j*48 + starts[f] + k];
        we[f] = s;
        row[1+f] = s;
    }
    #pragma unroll
    for (int c = 0; c < NC; ++c) row[19+c] = w2[c*HID + j];
    row[35] = 0.f;
    // w1 B-frags: col = j
    #pragma unroll
    for (int g = 0; g < 4; ++g)
        #pragma unroll
        for (int r = 0; r < 8; ++r) {
            int k = g*8 + r;
            w1pb[(j*4 + g)*8 + r] = f2bf(k < 18 ? we[k] : 0.f);
        }
    // w2 B-frags: k = j
    {
        int kc = j >> 5, g = (j >> 3) & 3, r = j & 7;
        #pragma unroll
        for (int ch = 0; ch < NC; ++ch)
            w2pb[((kc*4 + g)*16 + ch)*8 + r] = f2bf(w2[ch*HID + j]);
    }
}

// ---------------- fused NCA step ----------------
__global__ __launch_bounds__(NTHREADS, 2)
void nca_fused(const float* __restrict__ X,
               const float* __restrict__ rand_u,
               const float* __restrict__ wpack,
               const unsigned short* __restrict__ w1pb,
               const unsigned short* __restrict__ w2pb,
               float* __restrict__ out) {
    __shared__ __align__(16) float sX[NC][XSR][XSC];       // 30720 B, zero-padded OOB
    __shared__ __align__(16) unsigned short feat[336][FSTR]; // 26880 B (bf16), dx overlaid later
    __shared__ __align__(16) unsigned short hb[4][16][HSTR]; // 17408 B per-wave h
    __shared__ float sA[HR][HR];     // post-update alpha (fp32, fallback-corrected)
    __shared__ float sM[NPIX];       // stochastic mask (0/1)
    __shared__ float sDX3[NPIX];     // fp32 dx for alpha channel

    const int t    = threadIdx.x;
    const int x0   = blockIdx.x * TILE;
    const int y0   = blockIdx.y * TILE;
    const int b    = blockIdx.z;
    const int lane = t & 63;
    const int c15  = lane & 15;
    const int g    = lane >> 4;
    const int wave = t >> 6;

    const float* Xb = X + (size_t)b * NC * IMH * IMW;

    // ---- weight fragments (once per block; wave-shaped global b128 loads) ----
    bf16x8 w1f[8];
    #pragma unroll
    for (int nt = 0; nt < 8; ++nt)
        w1f[nt] = *(const bf16x8*)(w1pb + ((nt*16 + c15)*4 + g)*8);
    bf16x8 w2f[4];
    #pragma unroll
    for (int kc = 0; kc < 4; ++kc)
        w2f[kc] = *(const bf16x8*)(w2pb + ((kc*4 + g)*16 + c15)*8);
    float b1v[8], w23[8];
    #pragma unroll
    for (int nt = 0; nt < 8; ++nt) {
        b1v[nt] = wpack[(nt*16 + c15)*WROW + 0];
        w23[nt] = wpack[(nt*16 + c15)*WROW + 22];   // w2[3][nt*16+c15]
    }

    // ---- phase 1: stage X (16 ch x 20 rows x 24 cols, aligned float4 chunks) ----
    for (int u = t; u < NC*XSR; u += NTHREADS) {
        int ch = u / XSR, row = u % XSR;
        int gy = y0 + row - 2;
        bool yok = (gy >= 0 && gy < IMH);
        const float* src = Xb + (size_t)ch*IMH*IMW + (size_t)(yok ? gy : 0)*IMW;
        float4 z = {0.f,0.f,0.f,0.f};
        float4 c0 = (yok && x0 > 0)   ? *(const float4*)(src + x0 - 4)  : z;
        float4 c1 = yok               ? *(const float4*)(src + x0)      : z;
        float4 c2 = yok               ? *(const float4*)(src + x0 + 4)  : z;
        float4 c3 = yok               ? *(const float4*)(src + x0 + 8)  : z;
        float4 c4 = yok               ? *(const float4*)(src + x0 + 12) : z;
        float4 c5 = (yok && x0 < 240) ? *(const float4*)(src + x0 + 16) : z;
        *(float4*)&sX[ch][row][0]  = c0;
        *(float4*)&sX[ch][row][4]  = c1;
        *(float4*)&sX[ch][row][8]  = c2;
        *(float4*)&sX[ch][row][12] = c3;
        *(float4*)&sX[ch][row][16] = c4;
        *(float4*)&sX[ch][row][20] = c5;
    }

    // ---- stochastic mask (0 for OOB halo pixels) ----
    #pragma unroll
    for (int pass = 0; pass < 2; ++pass) {
        int pid = t + pass*NTHREADS;
        if (pid < NPIX) {
            int py = pid / HR, px = pid - py*HR;
            int gy = y0 + py - 1, gx = x0 + px - 1;
            float mv = 0.f;
            if (gy >= 0 && gy < IMH && gx >= 0 && gx < IMW)
                mv = (rand_u[((size_t)b << 16) + (gy << 8) + gx] < 0.5f) ? 1.f : 0.f;
            sM[pid] = mv;
        }
    }

    // ---- pre-zero feat pad (k24..39 of every row; all of pad rows 324..335) ----
    {
        int4 z4 = {0,0,0,0};
        for (int rr = t; rr < 336; rr += NTHREADS) {
            *(int4*)&feat[rr][24] = z4;
            *(int4*)&feat[rr][32] = z4;
        }
        if (t < 12) {
            int rr = 324 + t;
            *(int4*)&feat[rr][0]  = z4;
            *(int4*)&feat[rr][8]  = z4;
            *(int4*)&feat[rr][16] = z4;
        }
    }
    __syncthreads();

    // ---- phase 2: features (strip of 4 px per thread; 90 strips) ----
    if (t < 90) {
        const int srow = t / 5, xb = (t % 5) * 4;
        const int npx = (xb == 16) ? 2 : 4;   // px 16,17 valid; 18,19 discarded
        float r0[6], r1[6], r2[6];
        float fv[4][8];

#define LOAD6(dst, ch, rr) do { \
        float2 a_ = *(const float2*)&sX[ch][rr][xb+2]; \
        float2 b_ = *(const float2*)&sX[ch][rr][xb+4]; \
        float2 c_ = *(const float2*)&sX[ch][rr][xb+6]; \
        dst[0]=a_.x; dst[1]=a_.y; dst[2]=b_.x; dst[3]=b_.y; dst[4]=c_.x; dst[5]=c_.y; } while(0)
#define SOBX(j) (((r0[(j)+2]-r0[(j)]) + 2.f*(r1[(j)+2]-r1[(j)]) + (r2[(j)+2]-r2[(j)])) * 0.125f)
#define SOBY(j) (((r2[(j)] + 2.f*r2[(j)+1] + r2[(j)+2]) - (r0[(j)] + 2.f*r0[(j)+1] + r0[(j)+2])) * 0.125f)

        // chunk 0: k0..7 = ident ch0..5, sx ch5, sx ch6
        #pragma unroll
        for (int ch = 0; ch < 5; ++ch) {
            LOAD6(r1, ch, srow+1);
            #pragma unroll
            for (int j = 0; j < 4; ++j) fv[j][ch] = r1[j+1];
        }
        LOAD6(r0, 5, srow); LOAD6(r1, 5, srow+1); LOAD6(r2, 5, srow+2);
        #pragma unroll
        for (int j = 0; j < 4; ++j) { fv[j][5] = r1[j+1]; fv[j][6] = SOBX(j); }
        LOAD6(r0, 6, srow); LOAD6(r1, 6, srow+1); LOAD6(r2, 6, srow+2);
        #pragma unroll
        for (int j = 0; j < 4; ++j) fv[j][7] = SOBX(j);
        #pragma unroll
        for (int j = 0; j < 4; ++j) {
            if (j < npx) {
                int pid = srow*HR + xb + j;
                int4 v = { (int)(f2bf(fv[j][0]) | ((unsigned)f2bf(fv[j][1])<<16)),
                           (int)(f2bf(fv[j][2]) | ((unsigned)f2bf(fv[j][3])<<16)),
                           (int)(f2bf(fv[j][4]) | ((unsigned)f2bf(fv[j][5])<<16)),
                           (int)(f2bf(fv[j][6]) | ((unsigned)f2bf(fv[j][7])<<16)) };
                *(int4*)&feat[pid][0] = v;
            }
        }
        // chunk 1: k8..15 = sx ch7,8,9, sx ch10, sy ch10, sy ch11,12,13
        #pragma unroll
        for (int i = 0; i < 3; ++i) {
            int ch = 7 + i;
            LOAD6(r0, ch, srow); LOAD6(r1, ch, srow+1); LOAD6(r2, ch, srow+2);
            #pragma unroll
            for (int j = 0; j < 4; ++j) fv[j][i] = SOBX(j);
        }
        LOAD6(r0, 10, srow); LOAD6(r1, 10, srow+1); LOAD6(r2, 10, srow+2);
        #pragma unroll
        for (int j = 0; j < 4; ++j) { fv[j][3] = SOBX(j); fv[j][4] = SOBY(j); }
        #pragma unroll
        for (int i = 0; i < 3; ++i) {
            int ch = 11 + i;
            LOAD6(r0, ch, srow); LOAD6(r1, ch, srow+1); LOAD6(r2, ch, srow+2);
            #pragma unroll
            for (int j = 0; j < 4; ++j) fv[j][5+i] = SOBY(j);
        }
        #pragma unroll
        for (int j = 0; j < 4; ++j) {
            if (j < npx) {
                int pid = srow*HR + xb + j;
                int4 v = { (int)(f2bf(fv[j][0]) | ((unsigned)f2bf(fv[j][1])<<16)),
                           (int)(f2bf(fv[j][2]) | ((unsigned)f2bf(fv[j][3])<<16)),
                           (int)(f2bf(fv[j][4]) | ((unsigned)f2bf(fv[j][5])<<16)),
                           (int)(f2bf(fv[j][6]) | ((unsigned)f2bf(fv[j][7])<<16)) };
                *(int4*)&feat[pid][8] = v;
            }
        }
        // chunk 2: k16..23 = sy ch14, sy ch15, zeros
        #pragma unroll
        for (int i = 0; i < 2; ++i) {
            int ch = 14 + i;
            LOAD6(r0, ch, srow); LOAD6(r1, ch, srow+1); LOAD6(r2, ch, srow+2);
            #pragma unroll
            for (int j = 0; j < 4; ++j) fv[j][i] = SOBY(j);
        }
        #pragma unroll
        for (int j = 0; j < 4; ++j) {
            if (j < npx) {
                int pid = srow*HR + xb + j;
                int4 v = { (int)(f2bf(fv[j][0]) | ((unsigned)f2bf(fv[j][1])<<16)), 0, 0, 0 };
                *(int4*)&feat[pid][16] = v;
            }
        }
#undef LOAD6
#undef SOBX
#undef SOBY
    }
    __syncthreads();

    // ---- phase 3: MFMA MLP per 16-pixel tile ----
    #pragma unroll 1
    for (int tile = wave; tile < NTILES; tile += 4) {
        bf16x8 af = *(const bf16x8*)&feat[tile*16 + c15][g*8];
        f32x4 acc[8];
        #pragma unroll
        for (int nt = 0; nt < 8; ++nt) {
            f32x4 ci = { b1v[nt], b1v[nt], b1v[nt], b1v[nt] };
            acc[nt] = __builtin_amdgcn_mfma_f32_16x16x32_bf16(af, w1f[nt], ci, 0, 0, 0);
        }
        // relu -> h (bf16 to LDS) + fp32 partial for dx3
        float part[4] = {0.f, 0.f, 0.f, 0.f};
        #pragma unroll
        for (int nt = 0; nt < 8; ++nt)
            #pragma unroll
            for (int r = 0; r < 4; ++r) {
                float hv = fmaxf(acc[nt][r], 0.f);
                part[r] = fmaf(w23[nt], hv, part[r]);
                hb[wave][4*g + r][nt*16 + c15] = f2bf(hv);
            }
        // fp32 dx3: reduce over the 16 hidden-col lanes
        #pragma unroll
        for (int off = 1; off < 16; off <<= 1)
            #pragma unroll
            for (int r = 0; r < 4; ++r)
                part[r] += __shfl_xor(part[r], off, 16);
        if (c15 == 0) {
            #pragma unroll
            for (int r = 0; r < 4; ++r) {
                int pid = tile*16 + 4*g + r;
                if (pid < NPIX) sDX3[pid] = part[r];
            }
        }
        // layer 2 (bf16): dx for all 16 channels
        f32x4 dacc = {0.f, 0.f, 0.f, 0.f};
        #pragma unroll
        for (int kc = 0; kc < 4; ++kc) {
            bf16x8 ah = *(const bf16x8*)&hb[wave][c15][kc*32 + g*8];
            dacc = __builtin_amdgcn_mfma_f32_16x16x32_bf16(ah, w2f[kc], dacc, 0, 0, 0);
        }
        // dx (bf16) overlaid into this tile's feat rows (only its owner reads them)
        #pragma unroll
        for (int r = 0; r < 4; ++r) {
            int pid = tile*16 + 4*g + r;
            if (pid < NPIX) feat[pid][c15] = f2bf(dacc[r]);
        }
    }
    __syncthreads();

    // ---- phase 4: Xn alpha (fp32) + rare exact fallback near threshold ----
    #pragma unroll 1
    for (int pass = 0; pass < 2; ++pass) {
        int pid = t + pass*NTHREADS;
        if (pid < NPIX) {
            int py = pid / HR, px = pid - py*HR;
            float m   = sM[pid];
            float X3  = sX[3][py+1][px+3];
            float xn3 = fmaf(sDX3[pid], m, X3);
            if (m != 0.f && fabsf(xn3 - 0.1f) < 1e-3f) {
                // exact fp32 recompute (rare: ~1e-4 of pixels)
                float f[18];
                #pragma unroll
                for (int c = 0; c < 6; ++c) f[c] = sX[c][py+1][px+3];
                #pragma unroll
                for (int i = 0; i < 6; ++i) {
                    int ch = 5 + i;
                    f[6+i] = ( -sX[ch][py][px+2]   + sX[ch][py][px+4]
                               -2.f*sX[ch][py+1][px+2] + 2.f*sX[ch][py+1][px+4]
                               -sX[ch][py+2][px+2] + sX[ch][py+2][px+4] ) * 0.125f;
                }
                #pragma unroll
                for (int i = 0; i < 6; ++i) {
                    int ch = 10 + i;
                    f[12+i] = ( -sX[ch][py][px+2] - 2.f*sX[ch][py][px+3] - sX[ch][py][px+4]
                                +sX[ch][py+2][px+2] + 2.f*sX[ch][py+2][px+3] + sX[ch][py+2][px+4] ) * 0.125f;
                }
                float d3 = 0.f;
                for (int j = 0; j < HID; ++j) {
                    const float* row = wpack + j*WROW;
                    float hj = row[0];
                    #pragma unroll
                    for (int k = 0; k < 18; ++k) hj = fmaf(row[1+k], f[k], hj);
                    hj = fmaxf(hj, 0.f);
                    d3 = fmaf(row[22], hj, d3);
                }
                xn3 = X3 + d3;   // m == 1 here
            }
            sA[py][px] = xn3;
        }
    }
    __syncthreads();

    // ---- phase 5: live masks + output (interior 16x16 only) ----
    #pragma unroll 1
    for (int pass = 0; pass < 2; ++pass) {
        int pid = t + pass*NTHREADS;
        if (pid < NPIX) {
            int py = pid / HR, px = pid - py*HR;
            if (py >= 1 && py <= TILE && px >= 1 && px <= TILE) {
                float mpre = sX[3][py][px+2], mpost = sA[py-1][px-1];
                #pragma unroll
                for (int dy = 0; dy < 3; ++dy)
                    #pragma unroll
                    for (int dxx = 0; dxx < 3; ++dxx) {
                        mpre  = fmaxf(mpre,  sX[3][py+dy][px+dxx+2]);
                        mpost = fmaxf(mpost, sA[py-1+dy][px-1+dxx]);
                    }
                float live = (mpre > 0.1f && mpost > 0.1f) ? 1.f : 0.f;
                float m = sM[pid];
                int gy = y0 + py - 1, gx = x0 + px - 1;
                float* ob = out + ((size_t)b*NC)*IMH*IMW + (size_t)gy*IMW + gx;
                // dx (bf16) for all channels from the feat overlay
                int4 da = *(const int4*)&feat[pid][0];
                int4 db = *(const int4*)&feat[pid][8];
                unsigned short dxu[16];
                *(int4*)&dxu[0] = da;
                *(int4*)&dxu[8] = db;
                #pragma unroll
                for (int c = 0; c < NC; ++c) {
                    float val = (c == 3) ? sA[py][px]
                                         : fmaf(bf2f(dxu[c]), m, sX[c][py+1][px+3]);
                    ob[(size_t)c*IMH*IMW] = val * live;
                }
            }
        }
    }
}

extern "C" void kernel_launch(void* const* d_in, const int* in_sizes, int n_in,
                              void* d_out, int out_size, void* d_ws, size_t ws_size,
                              hipStream_t stream) {
    const float* X  = (const float*)d_in[0];
    const float* w1 = (const float*)d_in[1];
    const float* b1 = (const float*)d_in[2];
    const float* w2 = (const float*)d_in[3];
    const float* ru = (const float*)d_in[4];
    float* out = (float*)d_out;

    float* wpack = (float*)d_ws;                                   // 18432 B
    unsigned short* w1pb = (unsigned short*)((char*)d_ws + 18432); // 8192 B
    unsigned short* w2pb = (unsigned short*)((char*)d_ws + 26624); // 4096 B

    prep_weights<<<1, 128, 0, stream>>>(w1, b1, w2, wpack, w1pb, w2pb);

    dim3 grid(IMW/TILE, IMH/TILE, NB);
    nca_fused<<<grid, NTHREADS, 0, stream>>>(X, ru, wpack, w1pb, w2pb, out);
}